// Round 5
// baseline (403.231 us; speedup 1.0000x reference)
//
#include <hip/hip_runtime.h>
#include <hip/hip_bf16.h>
#include <hip/hip_fp16.h>

#define N_TOKENS 16384
#define D_IN 768
#define N_EXPERTS 8
#define EXPERT_DIM 2048

#define ROUTER_BLOCKS 256
#define TOK_PER_BLOCK 64

typedef _Float16 half8 __attribute__((ext_vector_type(8)));
typedef _Float16 half4 __attribute__((ext_vector_type(4)));
typedef float floatx4 __attribute__((ext_vector_type(4)));

// ---- 256-wide GEMM geometry (8 waves = 2m x 4n, per-wave 128xWN out, BK=64) ----
#define GBM 256
#define GBK 64
// Row = 128B = 8 chunks of 16B. Swizzle: chunk c of row r at phys chunk (c + r) & 7.
// (full-r rotation: an 8-lane ds_read_b128 phase = 8 consecutive rows, same logical
// chunk -> 8 DISTINCT phys chunks -> all 32 banks -> conflict-free. The r>>1 variant
// measured 4.9M conflict cycles in r4.)
// Store side (glds16 linear dest): row mod 8 == lane>>3, phys chunk == lane&7, so
// the per-lane GLOBAL source chunk is c_st = ((lane&7) - (lane>>3)) & 7  (w,q-independent).
// Read side: logical chunk kk*4+hi (hi=lane>>4), row mod 8 == lane&7, so
// phys = (kk*4 + hi + lane) & 7 -> c0 = ((lane>>4) + (lane&7)) & 7, kk=1 is c0^4.

// s_waitcnt imm (gfx9): vmcnt[3:0] | expcnt<<4 | lgkmcnt<<8 | vmcnt[5:4]<<14
#define WAIT_VM0 0xF70   // vmcnt(0)

__device__ __forceinline__ void glds16(const _Float16* g, _Float16* l) {
    __builtin_amdgcn_global_load_lds(
        (const __attribute__((address_space(1))) unsigned int*)g,
        (__attribute__((address_space(3))) unsigned int*)l, 16, 0, 0);
}

// ---------------- Fused router + act fp32->f16 (single pass over act) ----------------
// grid ROUTER_BLOCKS x 256. Wave handles 16 tokens; lane covers elems lane*4 + c*256, c=0..2.
__global__ __launch_bounds__(256) void router_convert(const float* __restrict__ act,
    const float* __restrict__ router_b, const float* __restrict__ router,
    _Float16* __restrict__ act_h, float* __restrict__ prob, int* __restrict__ localpos,
    int* __restrict__ eidx, int* __restrict__ hist)
{
    __shared__ int h[N_EXPERTS];
    if (threadIdx.x < N_EXPERTS) h[threadIdx.x] = 0;
    __syncthreads();

    int wave = threadIdx.x >> 6, lane = threadIdx.x & 63;

    // hoist router_b for this lane's 12 elems
    float rb[3][4];
#pragma unroll
    for (int c = 0; c < 3; ++c) {
        float4 v = *(const float4*)(router_b + lane * 4 + c * 256);
        rb[c][0] = v.x; rb[c][1] = v.y; rb[c][2] = v.z; rb[c][3] = v.w;
    }

#pragma unroll 1
    for (int it = 0; it < 16; ++it) {
        int t = blockIdx.x * TOK_PER_BLOCK + wave * 16 + it;
        const float* arow = act + (size_t)t * D_IN;
        float acc[8];
#pragma unroll
        for (int e = 0; e < 8; ++e) acc[e] = 0.f;
#pragma unroll
        for (int c = 0; c < 3; ++c) {
            int i0 = lane * 4 + c * 256;
            float4 v = *(const float4*)(arow + i0);
            half4 hv;
            hv[0] = (_Float16)v.x; hv[1] = (_Float16)v.y;
            hv[2] = (_Float16)v.z; hv[3] = (_Float16)v.w;
            *(half4*)(act_h + (size_t)t * D_IN + i0) = hv;
            float va[4] = {v.x, v.y, v.z, v.w};
#pragma unroll
            for (int q = 0; q < 4; ++q) {
                float a = va[q] - rb[c][q];
                const float* r = router + (size_t)(i0 + q) * 8;
#pragma unroll
                for (int e = 0; e < 8; ++e) acc[e] += a * r[e];
            }
        }
#pragma unroll
        for (int s = 32; s > 0; s >>= 1) {
#pragma unroll
            for (int e = 0; e < 8; ++e) acc[e] += __shfl_down(acc[e], s, 64);
        }
        if (lane == 0) {
            float m = acc[0]; int ai = 0;
#pragma unroll
            for (int e = 1; e < 8; ++e) if (acc[e] > m) { m = acc[e]; ai = e; }
            float s = 0.f;
#pragma unroll
            for (int e = 0; e < 8; ++e) s += __expf(acc[e] - m);
            prob[t] = 1.0f / s;
            eidx[t] = ai;
            localpos[t] = atomicAdd(&h[ai], 1);
        }
    }
    __syncthreads();
    if (threadIdx.x < N_EXPERTS) hist[blockIdx.x * N_EXPERTS + threadIdx.x] = h[threadIdx.x];
}

// ---------------- Phase 2: scan ----------------
__global__ __launch_bounds__(256) void scan_kernel(int* __restrict__ hist,
    int* __restrict__ counts, int* __restrict__ offsets)
{
    __shared__ int sh[ROUTER_BLOCKS * N_EXPERTS];
    __shared__ int tot[N_EXPERTS], off[N_EXPERTS];
    int tid = threadIdx.x;
    *(int4*)&sh[tid * 8]     = *(const int4*)&hist[tid * 8];
    *(int4*)&sh[tid * 8 + 4] = *(const int4*)&hist[tid * 8 + 4];
    __syncthreads();
    if (tid < N_EXPERTS) {
        int run = 0;
        for (int b = 0; b < ROUTER_BLOCKS; ++b) {
            int v = sh[b * 8 + tid];
            sh[b * 8 + tid] = run;
            run += v;
        }
        tot[tid] = run;
    }
    __syncthreads();
    if (tid == 0) {
        int run = 0;
        for (int e = 0; e < N_EXPERTS; ++e) {
            off[e] = run; offsets[e] = run; counts[e] = tot[e]; run += tot[e];
        }
    }
    __syncthreads();
    int4 a = *(const int4*)&sh[tid * 8];
    int4 b = *(const int4*)&sh[tid * 8 + 4];
    a.x += off[0]; a.y += off[1]; a.z += off[2]; a.w += off[3];
    b.x += off[4]; b.y += off[5]; b.z += off[6]; b.w += off[7];
    *(int4*)&hist[tid * 8]     = a;
    *(int4*)&hist[tid * 8 + 4] = b;
}

// ---------------- Phase 3: scatter ----------------
__global__ __launch_bounds__(256) void order_kernel(const int* __restrict__ eidx,
    const int* __restrict__ localpos, const int* __restrict__ hist,
    int* __restrict__ order)
{
    int t = blockIdx.x * 256 + threadIdx.x;
    int base = hist[(t >> 6) * N_EXPERTS + eidx[t]];
    order[base + localpos[t]] = t;
}

// ---------------- Weight transpose fp32 [E][K][Nc] -> f16 [E][Nc][K] ----------------
__global__ __launch_bounds__(256) void transpose_to_half(const float* __restrict__ W,
    _Float16* __restrict__ WT, int K, int Nc)
{
    __shared__ _Float16 tile[64][72];
    size_t esz = (size_t)K * Nc;
    const float* We = W + (size_t)blockIdx.z * esz;
    _Float16* WTe = WT + (size_t)blockIdx.z * esz;
    int n0 = blockIdx.x * 64, k0 = blockIdx.y * 64;
    int tr = threadIdx.x >> 4;
    int tc = threadIdx.x & 15;
#pragma unroll
    for (int rr = 0; rr < 64; rr += 16) {
        int k = k0 + rr + tr;
        float4 v = *(const float4*)(We + (size_t)k * Nc + n0 + tc * 4);
        tile[tc * 4 + 0][rr + tr] = (_Float16)v.x;
        tile[tc * 4 + 1][rr + tr] = (_Float16)v.y;
        tile[tc * 4 + 2][rr + tr] = (_Float16)v.z;
        tile[tc * 4 + 3][rr + tr] = (_Float16)v.w;
    }
    __syncthreads();
#pragma unroll
    for (int p = 0; p < 2; ++p) {
        int id = threadIdx.x + p * 256;
        int r = id >> 3, ch = id & 7;
        half8 v = *(const half8*)&tile[r][ch * 8];
        *(half8*)(WTe + (size_t)(n0 + r) * K + k0 + ch * 8) = v;
    }
}

// ---------------- Encode GEMM 256x256 (dbuf BK=64, conflict-free swizzle) ----------------
// grid 4096: e = id&7 (expert == XCD), j = id>>3: nt = j&7 (fastest), mt = j>>3.
__global__ __launch_bounds__(512, 2) void encode_kernel(const _Float16* __restrict__ act_h,
    const _Float16* __restrict__ encT, const int* __restrict__ order,
    const int* __restrict__ counts, const int* __restrict__ offsets,
    _Float16* __restrict__ latent)
{
    int id = blockIdx.x;
    int e = id & 7;
    int j = id >> 3;
    int nt = j & 7;
    int mt = j >> 3;

    int n_e = counts[e];
    if (mt * GBM >= n_e) return;
    int slot0 = offsets[e] + mt * GBM;
    int mrem = n_e - mt * GBM;

    __shared__ _Float16 lds[2][32768];
    __shared__ int s_tok[GBM];

    int tid = threadIdx.x;
    if (tid < GBM) s_tok[tid] = (tid < mrem) ? order[slot0 + tid] : order[slot0];
    __syncthreads();

    int w = tid >> 6, lane = tid & 63;
    int wm = w >> 2, wn = w & 3;
    int mrow = lane & 15;

    // staging: dst chunk lane&7 holds global chunk c_st of row w*8 + (lane>>3)
    int st_dst = w * 512 + lane * 8;
    int c_st = ((lane & 7) - (lane >> 3)) & 7;
    int row_st = w * 8 + (lane >> 3);
    const _Float16* Be = encT + (size_t)e * D_IN * EXPERT_DIM + (size_t)(nt * 256) * D_IN;
    const _Float16* pa0 = act_h + (size_t)s_tok[0 * 64 + row_st] * D_IN + c_st * 8;
    const _Float16* pa1 = act_h + (size_t)s_tok[1 * 64 + row_st] * D_IN + c_st * 8;
    const _Float16* pa2 = act_h + (size_t)s_tok[2 * 64 + row_st] * D_IN + c_st * 8;
    const _Float16* pa3 = act_h + (size_t)s_tok[3 * 64 + row_st] * D_IN + c_st * 8;
    const _Float16* pb0 = Be + (size_t)(0 * 64 + row_st) * D_IN + c_st * 8;
    const _Float16* pb1 = Be + (size_t)(1 * 64 + row_st) * D_IN + c_st * 8;
    const _Float16* pb2 = Be + (size_t)(2 * 64 + row_st) * D_IN + c_st * 8;
    const _Float16* pb3 = Be + (size_t)(3 * 64 + row_st) * D_IN + c_st * 8;

    // read: phys chunk (kk*4 + hi + row) & 7; row mod 8 == lane&7
    int c0 = ((lane >> 4) + (lane & 7)) & 7;
    int aoff0 = (wm * 128 + mrow) * 64 + c0 * 8;
    int aoff1 = (wm * 128 + mrow) * 64 + (c0 ^ 4) * 8;
    int boff0 = 16384 + (wn * 64 + mrow) * 64 + c0 * 8;
    int boff1 = 16384 + (wn * 64 + mrow) * 64 + (c0 ^ 4) * 8;

#define ENC_STAGE(bufp, k0h)                                           \
    do {                                                               \
        glds16(pa0 + (k0h), (bufp) + 0 * 4096 + st_dst);               \
        glds16(pa1 + (k0h), (bufp) + 1 * 4096 + st_dst);               \
        glds16(pa2 + (k0h), (bufp) + 2 * 4096 + st_dst);               \
        glds16(pa3 + (k0h), (bufp) + 3 * 4096 + st_dst);               \
        glds16(pb0 + (k0h), (bufp) + 16384 + 0 * 4096 + st_dst);       \
        glds16(pb1 + (k0h), (bufp) + 16384 + 1 * 4096 + st_dst);       \
        glds16(pb2 + (k0h), (bufp) + 16384 + 2 * 4096 + st_dst);       \
        glds16(pb3 + (k0h), (bufp) + 16384 + 3 * 4096 + st_dst);       \
    } while (0)

    floatx4 acc[8][4];
#pragma unroll
    for (int i = 0; i < 8; ++i)
#pragma unroll
        for (int jj = 0; jj < 4; ++jj) acc[i][jj] = (floatx4){0.f, 0.f, 0.f, 0.f};

    const int T = D_IN / GBK;   // 12
    ENC_STAGE(&lds[0][0], 0);
    __builtin_amdgcn_s_waitcnt(WAIT_VM0);
    __builtin_amdgcn_s_barrier();

#pragma unroll 1
    for (int t = 0; t < T; ++t) {
        _Float16* cur = &lds[t & 1][0];
        if (t + 1 < T) {
            _Float16* nxt = &lds[(t + 1) & 1][0];
            ENC_STAGE(nxt, (t + 1) * GBK);
        }
        half8 a0[8], b0[4];
#pragma unroll
        for (int i = 0; i < 8; ++i) a0[i] = *(const half8*)&cur[aoff0 + i * 1024];
#pragma unroll
        for (int jj = 0; jj < 4; ++jj) b0[jj] = *(const half8*)&cur[boff0 + jj * 1024];
        __builtin_amdgcn_s_setprio(1);
#pragma unroll
        for (int i = 0; i < 8; ++i)
#pragma unroll
            for (int jj = 0; jj < 4; ++jj)
                acc[i][jj] = __builtin_amdgcn_mfma_f32_16x16x32_f16(a0[i], b0[jj], acc[i][jj], 0, 0, 0);
        __builtin_amdgcn_s_setprio(0);
        half8 a1[8], b1[4];
#pragma unroll
        for (int i = 0; i < 8; ++i) a1[i] = *(const half8*)&cur[aoff1 + i * 1024];
#pragma unroll
        for (int jj = 0; jj < 4; ++jj) b1[jj] = *(const half8*)&cur[boff1 + jj * 1024];
        __builtin_amdgcn_s_setprio(1);
#pragma unroll
        for (int i = 0; i < 8; ++i)
#pragma unroll
            for (int jj = 0; jj < 4; ++jj)
                acc[i][jj] = __builtin_amdgcn_mfma_f32_16x16x32_f16(a1[i], b1[jj], acc[i][jj], 0, 0, 0);
        __builtin_amdgcn_s_setprio(0);
        if (t + 1 < T) {
            __builtin_amdgcn_s_waitcnt(WAIT_VM0);   // own staging loads, issued a full iter ago
            __builtin_amdgcn_s_barrier();
        }
    }
#undef ENC_STAGE

    // epilogue: ReLU -> latent f16
#pragma unroll
    for (int i = 0; i < 8; ++i) {
        int row0 = wm * 128 + i * 16 + (lane >> 4) * 4;
#pragma unroll
        for (int jj = 0; jj < 4; ++jj) {
            int col = nt * 256 + wn * 64 + jj * 16 + mrow;
#pragma unroll
            for (int r = 0; r < 4; ++r) {
                int row = row0 + r;
                if (row < mrem) {
                    float v = acc[i][jj][r];
                    v = v > 0.f ? v : 0.f;
                    latent[(size_t)(slot0 + row) * EXPERT_DIM + col] = (_Float16)v;
                }
            }
        }
    }
}

// ---------------- Decode GEMM 256x192 (dbuf BK=64, conflict-free swizzle, full fill) ----------------
// grid 2048: e = id&7, j = id>>3: nt = j&3 (fastest, 768/192=4), mt = j>>2.
// Active blocks = 8e x ~8mt x 4nt = 256 -> 100% CU fill (was 192/75% at GBN=256).
__global__ __launch_bounds__(512, 2) void decode_kernel(const _Float16* __restrict__ latent,
    const _Float16* __restrict__ decT, const int* __restrict__ order,
    const int* __restrict__ counts, const int* __restrict__ offsets,
    const float* __restrict__ prob, const float* __restrict__ pre_b,
    float* __restrict__ out)
{
    int id = blockIdx.x;
    int e = id & 7;
    int j = id >> 3;
    int nt = j & 3;
    int mt = j >> 2;

    int n_e = counts[e];
    if (mt * GBM >= n_e) return;
    int slot0 = offsets[e] + mt * GBM;
    int mrem = n_e - mt * GBM;

    // buffer: A 256x64 halves (16384) + B 192x64 halves (12288) = 28672 halves = 56KB
    __shared__ _Float16 lds[2][28672];
    __shared__ int s_tok[GBM];
    __shared__ float s_p[GBM];

    int tid = threadIdx.x;
    if (tid < GBM) {
        int tok = (tid < mrem) ? order[slot0 + tid] : order[slot0];
        s_tok[tid] = tok;
        s_p[tid] = prob[tok];
    }
    __syncthreads();

    int w = tid >> 6, lane = tid & 63;
    int wm = w >> 2, wn = w & 3;
    int mrow = lane & 15;

    int st_dst = w * 512 + lane * 8;
    int c_st = ((lane & 7) - (lane >> 3)) & 7;
    int row_st = w * 8 + (lane >> 3);
    const _Float16* Ae = latent + (size_t)slot0 * EXPERT_DIM;   // latent padded by GBM rows
    const _Float16* Be = decT + (size_t)e * EXPERT_DIM * D_IN + (size_t)(nt * 192) * EXPERT_DIM;
    const _Float16* pa0 = Ae + (size_t)(0 * 64 + row_st) * EXPERT_DIM + c_st * 8;
    const _Float16* pa1 = Ae + (size_t)(1 * 64 + row_st) * EXPERT_DIM + c_st * 8;
    const _Float16* pa2 = Ae + (size_t)(2 * 64 + row_st) * EXPERT_DIM + c_st * 8;
    const _Float16* pa3 = Ae + (size_t)(3 * 64 + row_st) * EXPERT_DIM + c_st * 8;
    const _Float16* pb0 = Be + (size_t)(0 * 64 + row_st) * EXPERT_DIM + c_st * 8;
    const _Float16* pb1 = Be + (size_t)(1 * 64 + row_st) * EXPERT_DIM + c_st * 8;
    const _Float16* pb2 = Be + (size_t)(2 * 64 + row_st) * EXPERT_DIM + c_st * 8;

    int c0 = ((lane >> 4) + (lane & 7)) & 7;
    int aoff0 = (wm * 128 + mrow) * 64 + c0 * 8;
    int aoff1 = (wm * 128 + mrow) * 64 + (c0 ^ 4) * 8;
    int boff0 = 16384 + (wn * 48 + mrow) * 64 + c0 * 8;
    int boff1 = 16384 + (wn * 48 + mrow) * 64 + (c0 ^ 4) * 8;

#define DEC_STAGE(bufp, k0h)                                           \
    do {                                                               \
        glds16(pa0 + (k0h), (bufp) + 0 * 4096 + st_dst);               \
        glds16(pa1 + (k0h), (bufp) + 1 * 4096 + st_dst);               \
        glds16(pa2 + (k0h), (bufp) + 2 * 4096 + st_dst);               \
        glds16(pa3 + (k0h), (bufp) + 3 * 4096 + st_dst);               \
        glds16(pb0 + (k0h), (bufp) + 16384 + 0 * 4096 + st_dst);       \
        glds16(pb1 + (k0h), (bufp) + 16384 + 1 * 4096 + st_dst);       \
        glds16(pb2 + (k0h), (bufp) + 16384 + 2 * 4096 + st_dst);       \
    } while (0)

    floatx4 acc[8][3];
#pragma unroll
    for (int i = 0; i < 8; ++i)
#pragma unroll
        for (int jj = 0; jj < 3; ++jj) acc[i][jj] = (floatx4){0.f, 0.f, 0.f, 0.f};

    const int T = EXPERT_DIM / GBK;   // 32
    DEC_STAGE(&lds[0][0], 0);
    __builtin_amdgcn_s_waitcnt(WAIT_VM0);
    __builtin_amdgcn_s_barrier();

#pragma unroll 1
    for (int t = 0; t < T; ++t) {
        _Float16* cur = &lds[t & 1][0];
        if (t + 1 < T) {
            _Float16* nxt = &lds[(t + 1) & 1][0];
            DEC_STAGE(nxt, (t + 1) * GBK);
        }
        half8 a0[8], b0[3];
#pragma unroll
        for (int i = 0; i < 8; ++i) a0[i] = *(const half8*)&cur[aoff0 + i * 1024];
#pragma unroll
        for (int jj = 0; jj < 3; ++jj) b0[jj] = *(const half8*)&cur[boff0 + jj * 1024];
        __builtin_amdgcn_s_setprio(1);
#pragma unroll
        for (int i = 0; i < 8; ++i)
#pragma unroll
            for (int jj = 0; jj < 3; ++jj)
                acc[i][jj] = __builtin_amdgcn_mfma_f32_16x16x32_f16(a0[i], b0[jj], acc[i][jj], 0, 0, 0);
        __builtin_amdgcn_s_setprio(0);
        half8 a1[8], b1[3];
#pragma unroll
        for (int i = 0; i < 8; ++i) a1[i] = *(const half8*)&cur[aoff1 + i * 1024];
#pragma unroll
        for (int jj = 0; jj < 3; ++jj) b1[jj] = *(const half8*)&cur[boff1 + jj * 1024];
        __builtin_amdgcn_s_setprio(1);
#pragma unroll
        for (int i = 0; i < 8; ++i)
#pragma unroll
            for (int jj = 0; jj < 3; ++jj)
                acc[i][jj] = __builtin_amdgcn_mfma_f32_16x16x32_f16(a1[i], b1[jj], acc[i][jj], 0, 0, 0);
        __builtin_amdgcn_s_setprio(0);
        if (t + 1 < T) {
            __builtin_amdgcn_s_waitcnt(WAIT_VM0);
            __builtin_amdgcn_s_barrier();
        }
    }
#undef DEC_STAGE

    // epilogue: prob-scale + bias, scatter to out (fp32)
#pragma unroll
    for (int i = 0; i < 8; ++i) {
        int row0 = wm * 128 + i * 16 + (lane >> 4) * 4;
#pragma unroll
        for (int jj = 0; jj < 3; ++jj) {
            int col = nt * 192 + wn * 48 + jj * 16 + mrow;
            float pb = pre_b[col];
#pragma unroll
            for (int r = 0; r < 4; ++r) {
                int row = row0 + r;
                if (row < mrem) {
                    out[(size_t)s_tok[row] * D_IN + col] = s_p[row] * acc[i][jj][r] + pb;
                }
            }
        }
    }
}

extern "C" void kernel_launch(void* const* d_in, const int* in_sizes, int n_in,
                              void* d_out, int out_size, void* d_ws, size_t ws_size,
                              hipStream_t stream)
{
    const float* act      = (const float*)d_in[0];
    const float* pre_b    = (const float*)d_in[1];
    const float* enc      = (const float*)d_in[2];
    const float* dec      = (const float*)d_in[3];
    const float* router_b = (const float*)d_in[4];
    const float* router   = (const float*)d_in[5];
    float* out = (float*)d_out;

    char* w = (char*)d_ws;
    int* counts  = (int*)w;  w += 256;
    int* offsets = (int*)w;  w += 256;
    int* hist    = (int*)w;  w += ROUTER_BLOCKS * N_EXPERTS * 4;
    int* eidx    = (int*)w;  w += N_TOKENS * 4;
    int* lpos    = (int*)w;  w += N_TOKENS * 4;
    int* order   = (int*)w;  w += N_TOKENS * 4;
    float* prob  = (float*)w; w += N_TOKENS * 4;
    _Float16* act_h  = (_Float16*)w; w += (size_t)N_TOKENS * D_IN * 2;
    _Float16* encT   = (_Float16*)w; w += (size_t)N_EXPERTS * D_IN * EXPERT_DIM * 2;
    _Float16* decT   = (_Float16*)w; w += (size_t)N_EXPERTS * D_IN * EXPERT_DIM * 2;
    _Float16* latent = (_Float16*)w; w += (size_t)(N_TOKENS + GBM) * EXPERT_DIM * 2;

    router_convert<<<ROUTER_BLOCKS, 256, 0, stream>>>(act, router_b, router, act_h, prob, lpos, eidx, hist);
    scan_kernel<<<1, 256, 0, stream>>>(hist, counts, offsets);
    order_kernel<<<N_TOKENS / 256, 256, 0, stream>>>(eidx, lpos, hist, order);

    transpose_to_half<<<dim3(EXPERT_DIM / 64, D_IN / 64, N_EXPERTS), 256, 0, stream>>>(enc, encT, D_IN, EXPERT_DIM);
    transpose_to_half<<<dim3(D_IN / 64, EXPERT_DIM / 64, N_EXPERTS), 256, 0, stream>>>(dec, decT, EXPERT_DIM, D_IN);

    encode_kernel<<<4096, 512, 0, stream>>>(act_h, encT, order, counts, offsets, latent);
    decode_kernel<<<2048, 512, 0, stream>>>(latent, decT, order, counts, offsets, prob, pre_b, out);
}

// Round 6
// 390.982 us; speedup vs baseline: 1.0313x; 1.0313x over previous
//
#include <hip/hip_runtime.h>
#include <hip/hip_bf16.h>
#include <hip/hip_fp16.h>

#define N_TOKENS 16384
#define D_IN 768
#define N_EXPERTS 8
#define EXPERT_DIM 2048

#define ROUTER_BLOCKS 256
#define TOK_PER_BLOCK 64

typedef _Float16 half8 __attribute__((ext_vector_type(8)));
typedef _Float16 half4 __attribute__((ext_vector_type(4)));
typedef float floatx4 __attribute__((ext_vector_type(4)));

// ---- 256x256 GEMM, BK=32, NBUF=4, depth-3 prefetch, counted vmcnt ----
// 8 waves = 2m x 4n, per-wave 128x64 out, acc[8][4].
// Buffer = A 256x32 + B 256x32 halves = 32KB; 4 buffers = 128KB LDS.
// Row = 64B = 4 chunks of 16B. Swizzle (r1-HW-verified, 0 conflicts):
//   logical chunk c of row r stored at phys chunk (c + (r>>1)) & 3.
// Store (glds16 linear dest): instr covers rows w*32+q*16+(lane>>2), phys chunk lane&3;
//   (r>>1)&3 == (lane>>3)&3 (w*16, q*8 == 0 mod 4) -> src chunk
//   c_st = ((lane&3) - ((lane>>3)&3)) & 3   (w,q-independent).
// Read (ds_read_b128): row = wm*128+i*16+mrow, logical chunk = lane>>4;
//   (r>>1)&3 == (mrow>>1)&3 -> fo = (((lane>>4)+(mrow>>1))&3)*8.
//   16-lane group spreads over 8 x 16B granules, 2 lanes each = free (m136).

// s_waitcnt imm (gfx9): vmcnt[3:0] | expcnt<<4 | lgkmcnt<<8 | vmcnt[5:4]<<14
#define WAIT_VM12 0xF7C  // 3 stages (12 loads) in flight; oldest tile landed
#define WAIT_VM8  0xF78
#define WAIT_VM4  0xF74
#define WAIT_VM0  0xF70

__device__ __forceinline__ void glds16(const _Float16* g, _Float16* l) {
    __builtin_amdgcn_global_load_lds(
        (const __attribute__((address_space(1))) unsigned int*)g,
        (__attribute__((address_space(3))) unsigned int*)l, 16, 0, 0);
}

// ---------------- Fused router + act fp32->f16 (single pass over act) ----------------
__global__ __launch_bounds__(256) void router_convert(const float* __restrict__ act,
    const float* __restrict__ router_b, const float* __restrict__ router,
    _Float16* __restrict__ act_h, float* __restrict__ prob, int* __restrict__ localpos,
    int* __restrict__ eidx, int* __restrict__ hist)
{
    __shared__ int h[N_EXPERTS];
    if (threadIdx.x < N_EXPERTS) h[threadIdx.x] = 0;
    __syncthreads();

    int wave = threadIdx.x >> 6, lane = threadIdx.x & 63;

    float rb[3][4];
#pragma unroll
    for (int c = 0; c < 3; ++c) {
        float4 v = *(const float4*)(router_b + lane * 4 + c * 256);
        rb[c][0] = v.x; rb[c][1] = v.y; rb[c][2] = v.z; rb[c][3] = v.w;
    }

#pragma unroll 1
    for (int it = 0; it < 16; ++it) {
        int t = blockIdx.x * TOK_PER_BLOCK + wave * 16 + it;
        const float* arow = act + (size_t)t * D_IN;
        float acc[8];
#pragma unroll
        for (int e = 0; e < 8; ++e) acc[e] = 0.f;
#pragma unroll
        for (int c = 0; c < 3; ++c) {
            int i0 = lane * 4 + c * 256;
            float4 v = *(const float4*)(arow + i0);
            half4 hv;
            hv[0] = (_Float16)v.x; hv[1] = (_Float16)v.y;
            hv[2] = (_Float16)v.z; hv[3] = (_Float16)v.w;
            *(half4*)(act_h + (size_t)t * D_IN + i0) = hv;
            float va[4] = {v.x, v.y, v.z, v.w};
#pragma unroll
            for (int q = 0; q < 4; ++q) {
                float a = va[q] - rb[c][q];
                const float* r = router + (size_t)(i0 + q) * 8;
#pragma unroll
                for (int e = 0; e < 8; ++e) acc[e] += a * r[e];
            }
        }
#pragma unroll
        for (int s = 32; s > 0; s >>= 1) {
#pragma unroll
            for (int e = 0; e < 8; ++e) acc[e] += __shfl_down(acc[e], s, 64);
        }
        if (lane == 0) {
            float m = acc[0]; int ai = 0;
#pragma unroll
            for (int e = 1; e < 8; ++e) if (acc[e] > m) { m = acc[e]; ai = e; }
            float s = 0.f;
#pragma unroll
            for (int e = 0; e < 8; ++e) s += __expf(acc[e] - m);
            prob[t] = 1.0f / s;
            eidx[t] = ai;
            localpos[t] = atomicAdd(&h[ai], 1);
        }
    }
    __syncthreads();
    if (threadIdx.x < N_EXPERTS) hist[blockIdx.x * N_EXPERTS + threadIdx.x] = h[threadIdx.x];
}

// ---------------- Phase 2: scan ----------------
__global__ __launch_bounds__(256) void scan_kernel(int* __restrict__ hist,
    int* __restrict__ counts, int* __restrict__ offsets)
{
    __shared__ int sh[ROUTER_BLOCKS * N_EXPERTS];
    __shared__ int tot[N_EXPERTS], off[N_EXPERTS];
    int tid = threadIdx.x;
    *(int4*)&sh[tid * 8]     = *(const int4*)&hist[tid * 8];
    *(int4*)&sh[tid * 8 + 4] = *(const int4*)&hist[tid * 8 + 4];
    __syncthreads();
    if (tid < N_EXPERTS) {
        int run = 0;
        for (int b = 0; b < ROUTER_BLOCKS; ++b) {
            int v = sh[b * 8 + tid];
            sh[b * 8 + tid] = run;
            run += v;
        }
        tot[tid] = run;
    }
    __syncthreads();
    if (tid == 0) {
        int run = 0;
        for (int e = 0; e < N_EXPERTS; ++e) {
            off[e] = run; offsets[e] = run; counts[e] = tot[e]; run += tot[e];
        }
    }
    __syncthreads();
    int4 a = *(const int4*)&sh[tid * 8];
    int4 b = *(const int4*)&sh[tid * 8 + 4];
    a.x += off[0]; a.y += off[1]; a.z += off[2]; a.w += off[3];
    b.x += off[4]; b.y += off[5]; b.z += off[6]; b.w += off[7];
    *(int4*)&hist[tid * 8]     = a;
    *(int4*)&hist[tid * 8 + 4] = b;
}

// ---------------- Phase 3: scatter ----------------
__global__ __launch_bounds__(256) void order_kernel(const int* __restrict__ eidx,
    const int* __restrict__ localpos, const int* __restrict__ hist,
    int* __restrict__ order)
{
    int t = blockIdx.x * 256 + threadIdx.x;
    int base = hist[(t >> 6) * N_EXPERTS + eidx[t]];
    order[base + localpos[t]] = t;
}

// ---------------- Weight transpose fp32 [E][K][Nc] -> f16 [E][Nc][K] ----------------
__global__ __launch_bounds__(256) void transpose_to_half(const float* __restrict__ W,
    _Float16* __restrict__ WT, int K, int Nc)
{
    __shared__ _Float16 tile[64][72];
    size_t esz = (size_t)K * Nc;
    const float* We = W + (size_t)blockIdx.z * esz;
    _Float16* WTe = WT + (size_t)blockIdx.z * esz;
    int n0 = blockIdx.x * 64, k0 = blockIdx.y * 64;
    int tr = threadIdx.x >> 4;
    int tc = threadIdx.x & 15;
#pragma unroll
    for (int rr = 0; rr < 64; rr += 16) {
        int k = k0 + rr + tr;
        float4 v = *(const float4*)(We + (size_t)k * Nc + n0 + tc * 4);
        tile[tc * 4 + 0][rr + tr] = (_Float16)v.x;
        tile[tc * 4 + 1][rr + tr] = (_Float16)v.y;
        tile[tc * 4 + 2][rr + tr] = (_Float16)v.z;
        tile[tc * 4 + 3][rr + tr] = (_Float16)v.w;
    }
    __syncthreads();
#pragma unroll
    for (int p = 0; p < 2; ++p) {
        int id = threadIdx.x + p * 256;
        int r = id >> 3, ch = id & 7;
        half8 v = *(const half8*)&tile[r][ch * 8];
        *(half8*)(WTe + (size_t)(n0 + r) * K + k0 + ch * 8) = v;
    }
}

// Staging per K-tile: 4 glds16/thread (A: q=0,1; B: q=0,1), rows w*32+q*16+(lane>>2).
// dst halves: A = w*1024 + q*512 + lane*8; B = 8192 + same.
#define STAGE(bufp, k0h)                                        \
    do {                                                        \
        glds16(pa0 + (k0h), (bufp) + st_base);                  \
        glds16(pa1 + (k0h), (bufp) + st_base + 512);            \
        glds16(pb0 + (k0h), (bufp) + 8192 + st_base);           \
        glds16(pb1 + (k0h), (bufp) + 8192 + st_base + 512);     \
    } while (0)

// ---------------- Encode GEMM 256x256 BK=32 NBUF=4 (expert->XCD, nt fastest) ----------------
// grid 4096: e = id&7, j = id>>3: nt = j&7, mt = j>>3 in [0,64).
__global__ __launch_bounds__(512, 2) void encode_kernel(const _Float16* __restrict__ act_h,
    const _Float16* __restrict__ encT, const int* __restrict__ order,
    const int* __restrict__ counts, const int* __restrict__ offsets,
    _Float16* __restrict__ latent)
{
    int id = blockIdx.x;
    int e = id & 7;
    int j = id >> 3;
    int nt = j & 7;
    int mt = j >> 3;

    int n_e = counts[e];
    if (mt * 256 >= n_e) return;
    int slot0 = offsets[e] + mt * 256;
    int mrem = n_e - mt * 256;

    __shared__ _Float16 lds[4][16384];
    __shared__ int s_tok[256];

    int tid = threadIdx.x;
    if (tid < 256) s_tok[tid] = (tid < mrem) ? order[slot0 + tid] : order[slot0];
    __syncthreads();

    int w = tid >> 6, lane = tid & 63;
    int wm = w >> 2, wn = w & 3;
    int mrow = lane & 15;

    // staging addressing
    int st_base = w * 1024 + lane * 8;
    int c_st = ((lane & 3) - ((lane >> 3) & 3)) & 3;
    int r_in = lane >> 2;               // 0..15
    const _Float16* Be = encT + (size_t)e * D_IN * EXPERT_DIM + (size_t)(nt * 256) * D_IN;
    const _Float16* pa0 = act_h + (size_t)s_tok[w * 32 + r_in] * D_IN + c_st * 8;
    const _Float16* pa1 = act_h + (size_t)s_tok[w * 32 + 16 + r_in] * D_IN + c_st * 8;
    const _Float16* pb0 = Be + (size_t)(w * 32 + r_in) * D_IN + c_st * 8;
    const _Float16* pb1 = Be + (size_t)(w * 32 + 16 + r_in) * D_IN + c_st * 8;

    // read addressing
    int fo = (((lane >> 4) + (mrow >> 1)) & 3) * 8;
    int aoff = (wm * 128 + mrow) * 32 + fo;          // + i*512
    int boff = 8192 + (wn * 64 + mrow) * 32 + fo;    // + j*512

    floatx4 acc[8][4];
#pragma unroll
    for (int i = 0; i < 8; ++i)
#pragma unroll
        for (int jj = 0; jj < 4; ++jj) acc[i][jj] = (floatx4){0.f, 0.f, 0.f, 0.f};

    const int T = D_IN / 32;   // 24
    STAGE(&lds[0][0], 0);
    STAGE(&lds[1][0], 32);
    STAGE(&lds[2][0], 64);

#pragma unroll 1
    for (int t = 0; t < T; ++t) {
        _Float16* cur = &lds[t & 3][0];
        if (t + 3 < T) {
            STAGE(&lds[(t + 3) & 3][0], (t + 3) * 32);
            __builtin_amdgcn_s_waitcnt(WAIT_VM12);
        } else if (t + 2 < T) {
            __builtin_amdgcn_s_waitcnt(WAIT_VM8);
        } else if (t + 1 < T) {
            __builtin_amdgcn_s_waitcnt(WAIT_VM4);
        } else {
            __builtin_amdgcn_s_waitcnt(WAIT_VM0);
        }
        __builtin_amdgcn_s_barrier();
        half8 af[8], bf[4];
#pragma unroll
        for (int i = 0; i < 8; ++i) af[i] = *(const half8*)&cur[aoff + i * 512];
#pragma unroll
        for (int jj = 0; jj < 4; ++jj) bf[jj] = *(const half8*)&cur[boff + jj * 512];
        __builtin_amdgcn_s_setprio(1);
#pragma unroll
        for (int i = 0; i < 8; ++i)
#pragma unroll
            for (int jj = 0; jj < 4; ++jj)
                acc[i][jj] = __builtin_amdgcn_mfma_f32_16x16x32_f16(af[i], bf[jj], acc[i][jj], 0, 0, 0);
        __builtin_amdgcn_s_setprio(0);
        __builtin_amdgcn_s_barrier();   // all waves done reading buf before reuse as t+4's target
    }

    // epilogue: ReLU -> latent f16
#pragma unroll
    for (int i = 0; i < 8; ++i) {
        int row0 = wm * 128 + i * 16 + (lane >> 4) * 4;
#pragma unroll
        for (int jj = 0; jj < 4; ++jj) {
            int col = nt * 256 + wn * 64 + jj * 16 + mrow;
#pragma unroll
            for (int r = 0; r < 4; ++r) {
                int row = row0 + r;
                if (row < mrem) {
                    float v = acc[i][jj][r];
                    v = v > 0.f ? v : 0.f;
                    latent[(size_t)(slot0 + row) * EXPERT_DIM + col] = (_Float16)v;
                }
            }
        }
    }
}

// ---------------- Decode GEMM 256x256 BK=32 NBUF=4 (expert->XCD, nt fastest) ----------------
// grid 1536: e = id&7, j = id>>3 in [0,192): nt = j%3, mt = j/3 in [0,64).
// Worst expert: 9 mt x 3 nt = 27 blocks/XCD <= 32 CUs -> single residency round.
__global__ __launch_bounds__(512, 2) void decode_kernel(const _Float16* __restrict__ latent,
    const _Float16* __restrict__ decT, const int* __restrict__ order,
    const int* __restrict__ counts, const int* __restrict__ offsets,
    const float* __restrict__ prob, const float* __restrict__ pre_b,
    float* __restrict__ out)
{
    int id = blockIdx.x;
    int e = id & 7;
    int j = id >> 3;
    int nt = j % 3;
    int mt = j / 3;

    int n_e = counts[e];
    if (mt * 256 >= n_e) return;
    int slot0 = offsets[e] + mt * 256;
    int mrem = n_e - mt * 256;

    __shared__ _Float16 lds[4][16384];
    __shared__ int s_tok[256];
    __shared__ float s_p[256];

    int tid = threadIdx.x;
    if (tid < 256) {
        int tok = (tid < mrem) ? order[slot0 + tid] : order[slot0];
        s_tok[tid] = tok;
        s_p[tid] = prob[tok];
    }
    __syncthreads();

    int w = tid >> 6, lane = tid & 63;
    int wm = w >> 2, wn = w & 3;
    int mrow = lane & 15;

    int st_base = w * 1024 + lane * 8;
    int c_st = ((lane & 3) - ((lane >> 3) & 3)) & 3;
    int r_in = lane >> 2;
    const _Float16* Ae = latent + (size_t)slot0 * EXPERT_DIM;   // latent padded by 256 rows
    const _Float16* Be = decT + (size_t)e * EXPERT_DIM * D_IN + (size_t)(nt * 256) * EXPERT_DIM;
    const _Float16* pa0 = Ae + (size_t)(w * 32 + r_in) * EXPERT_DIM + c_st * 8;
    const _Float16* pa1 = Ae + (size_t)(w * 32 + 16 + r_in) * EXPERT_DIM + c_st * 8;
    const _Float16* pb0 = Be + (size_t)(w * 32 + r_in) * EXPERT_DIM + c_st * 8;
    const _Float16* pb1 = Be + (size_t)(w * 32 + 16 + r_in) * EXPERT_DIM + c_st * 8;

    int fo = (((lane >> 4) + (mrow >> 1)) & 3) * 8;
    int aoff = (wm * 128 + mrow) * 32 + fo;
    int boff = 8192 + (wn * 64 + mrow) * 32 + fo;

    floatx4 acc[8][4];
#pragma unroll
    for (int i = 0; i < 8; ++i)
#pragma unroll
        for (int jj = 0; jj < 4; ++jj) acc[i][jj] = (floatx4){0.f, 0.f, 0.f, 0.f};

    const int T = EXPERT_DIM / 32;   // 64
    STAGE(&lds[0][0], 0);
    STAGE(&lds[1][0], 32);
    STAGE(&lds[2][0], 64);

#pragma unroll 1
    for (int t = 0; t < T; ++t) {
        _Float16* cur = &lds[t & 3][0];
        if (t + 3 < T) {
            STAGE(&lds[(t + 3) & 3][0], (t + 3) * 32);
            __builtin_amdgcn_s_waitcnt(WAIT_VM12);
        } else if (t + 2 < T) {
            __builtin_amdgcn_s_waitcnt(WAIT_VM8);
        } else if (t + 1 < T) {
            __builtin_amdgcn_s_waitcnt(WAIT_VM4);
        } else {
            __builtin_amdgcn_s_waitcnt(WAIT_VM0);
        }
        __builtin_amdgcn_s_barrier();
        half8 af[8], bf[4];
#pragma unroll
        for (int i = 0; i < 8; ++i) af[i] = *(const half8*)&cur[aoff + i * 512];
#pragma unroll
        for (int jj = 0; jj < 4; ++jj) bf[jj] = *(const half8*)&cur[boff + jj * 512];
        __builtin_amdgcn_s_setprio(1);
#pragma unroll
        for (int i = 0; i < 8; ++i)
#pragma unroll
            for (int jj = 0; jj < 4; ++jj)
                acc[i][jj] = __builtin_amdgcn_mfma_f32_16x16x32_f16(af[i], bf[jj], acc[i][jj], 0, 0, 0);
        __builtin_amdgcn_s_setprio(0);
        __builtin_amdgcn_s_barrier();
    }

    // epilogue: prob-scale + bias, scatter to out (fp32)
#pragma unroll
    for (int i = 0; i < 8; ++i) {
        int row0 = wm * 128 + i * 16 + (lane >> 4) * 4;
#pragma unroll
        for (int jj = 0; jj < 4; ++jj) {
            int col = nt * 256 + wn * 64 + jj * 16 + mrow;
            float pb = pre_b[col];
#pragma unroll
            for (int r = 0; r < 4; ++r) {
                int row = row0 + r;
                if (row < mrem) {
                    out[(size_t)s_tok[row] * D_IN + col] = s_p[row] * acc[i][jj][r] + pb;
                }
            }
        }
    }
}

extern "C" void kernel_launch(void* const* d_in, const int* in_sizes, int n_in,
                              void* d_out, int out_size, void* d_ws, size_t ws_size,
                              hipStream_t stream)
{
    const float* act      = (const float*)d_in[0];
    const float* pre_b    = (const float*)d_in[1];
    const float* enc      = (const float*)d_in[2];
    const float* dec      = (const float*)d_in[3];
    const float* router_b = (const float*)d_in[4];
    const float* router   = (const float*)d_in[5];
    float* out = (float*)d_out;

    char* w = (char*)d_ws;
    int* counts  = (int*)w;  w += 256;
    int* offsets = (int*)w;  w += 256;
    int* hist    = (int*)w;  w += ROUTER_BLOCKS * N_EXPERTS * 4;
    int* eidx    = (int*)w;  w += N_TOKENS * 4;
    int* lpos    = (int*)w;  w += N_TOKENS * 4;
    int* order   = (int*)w;  w += N_TOKENS * 4;
    float* prob  = (float*)w; w += N_TOKENS * 4;
    _Float16* act_h  = (_Float16*)w; w += (size_t)N_TOKENS * D_IN * 2;
    _Float16* encT   = (_Float16*)w; w += (size_t)N_EXPERTS * D_IN * EXPERT_DIM * 2;
    _Float16* decT   = (_Float16*)w; w += (size_t)N_EXPERTS * D_IN * EXPERT_DIM * 2;
    _Float16* latent = (_Float16*)w; w += (size_t)(N_TOKENS + 256) * EXPERT_DIM * 2;

    router_convert<<<ROUTER_BLOCKS, 256, 0, stream>>>(act, router_b, router, act_h, prob, lpos, eidx, hist);
    scan_kernel<<<1, 256, 0, stream>>>(hist, counts, offsets);
    order_kernel<<<N_TOKENS / 256, 256, 0, stream>>>(eidx, lpos, hist, order);

    transpose_to_half<<<dim3(EXPERT_DIM / 64, D_IN / 64, N_EXPERTS), 256, 0, stream>>>(enc, encT, D_IN, EXPERT_DIM);
    transpose_to_half<<<dim3(D_IN / 64, EXPERT_DIM / 64, N_EXPERTS), 256, 0, stream>>>(dec, decT, EXPERT_DIM, D_IN);

    encode_kernel<<<4096, 512, 0, stream>>>(act_h, encT, order, counts, offsets, latent);
    decode_kernel<<<1536, 512, 0, stream>>>(latent, decT, order, counts, offsets, prob, pre_b, out);
}

// Round 7
// 370.665 us; speedup vs baseline: 1.0879x; 1.0548x over previous
//
#include <hip/hip_runtime.h>
#include <hip/hip_bf16.h>
#include <hip/hip_fp16.h>

#define N_TOKENS 16384
#define D_IN 768
#define N_EXPERTS 8
#define EXPERT_DIM 2048

#define ROUTER_BLOCKS 256
#define TOK_PER_BLOCK 64

typedef _Float16 half8 __attribute__((ext_vector_type(8)));
typedef _Float16 half4 __attribute__((ext_vector_type(4)));
typedef float floatx4 __attribute__((ext_vector_type(4)));

// ---- 256x256 GEMM, BK=32, NBUF=4, depth-3 prefetch, 2-phase/K-step interleave ----
// Addressing/swizzle identical to r6 (SQ_LDS_BANK_CONFLICT == 0 verified):
//   store: phys chunk lane&3 <- logical chunk c_st = ((lane&3)-((lane>>3)&3))&3
//   read:  fo = (((lane>>4)+(mrow>>1))&3)*8
// NEW (m201 8-phase port): each K-step = 2 phases of 16 MFMA:
//   phase { ds_read subtile; issue 2 stage loads; s_barrier; [lgkm by compiler];
//           setprio(1); 16 MFMA; setprio(0); s_barrier }
// Counted vmcnt ONCE per K-step, before the iter-boundary barrier (never 0 mid-loop):
//   after staging t+3, in-flight = {t+1,t+2,t+3} = 12 loads -> vmcnt(8) ensures t+1 landed.

// s_waitcnt imm (gfx9): vmcnt[3:0] | expcnt<<4 | lgkmcnt<<8 | vmcnt[5:4]<<14
#define WAIT_VM8  0xF78
#define WAIT_VM4  0xF74
#define WAIT_VM0  0xF70

__device__ __forceinline__ void glds16(const _Float16* g, _Float16* l) {
    __builtin_amdgcn_global_load_lds(
        (const __attribute__((address_space(1))) unsigned int*)g,
        (__attribute__((address_space(3))) unsigned int*)l, 16, 0, 0);
}

// ---------------- Fused router + act fp32->f16 ----------------
__global__ __launch_bounds__(256) void router_convert(const float* __restrict__ act,
    const float* __restrict__ router_b, const float* __restrict__ router,
    _Float16* __restrict__ act_h, float* __restrict__ prob, int* __restrict__ localpos,
    int* __restrict__ eidx, int* __restrict__ hist)
{
    __shared__ int h[N_EXPERTS];
    if (threadIdx.x < N_EXPERTS) h[threadIdx.x] = 0;
    __syncthreads();

    int wave = threadIdx.x >> 6, lane = threadIdx.x & 63;

    float rb[3][4];
#pragma unroll
    for (int c = 0; c < 3; ++c) {
        float4 v = *(const float4*)(router_b + lane * 4 + c * 256);
        rb[c][0] = v.x; rb[c][1] = v.y; rb[c][2] = v.z; rb[c][3] = v.w;
    }

#pragma unroll 1
    for (int it = 0; it < 16; ++it) {
        int t = blockIdx.x * TOK_PER_BLOCK + wave * 16 + it;
        const float* arow = act + (size_t)t * D_IN;
        float acc[8];
#pragma unroll
        for (int e = 0; e < 8; ++e) acc[e] = 0.f;
#pragma unroll
        for (int c = 0; c < 3; ++c) {
            int i0 = lane * 4 + c * 256;
            float4 v = *(const float4*)(arow + i0);
            half4 hv;
            hv[0] = (_Float16)v.x; hv[1] = (_Float16)v.y;
            hv[2] = (_Float16)v.z; hv[3] = (_Float16)v.w;
            *(half4*)(act_h + (size_t)t * D_IN + i0) = hv;
            float va[4] = {v.x, v.y, v.z, v.w};
#pragma unroll
            for (int q = 0; q < 4; ++q) {
                float a = va[q] - rb[c][q];
                const float* r = router + (size_t)(i0 + q) * 8;
#pragma unroll
                for (int e = 0; e < 8; ++e) acc[e] += a * r[e];
            }
        }
#pragma unroll
        for (int s = 32; s > 0; s >>= 1) {
#pragma unroll
            for (int e = 0; e < 8; ++e) acc[e] += __shfl_down(acc[e], s, 64);
        }
        if (lane == 0) {
            float m = acc[0]; int ai = 0;
#pragma unroll
            for (int e = 1; e < 8; ++e) if (acc[e] > m) { m = acc[e]; ai = e; }
            float s = 0.f;
#pragma unroll
            for (int e = 0; e < 8; ++e) s += __expf(acc[e] - m);
            prob[t] = 1.0f / s;
            eidx[t] = ai;
            localpos[t] = atomicAdd(&h[ai], 1);
        }
    }
    __syncthreads();
    if (threadIdx.x < N_EXPERTS) hist[blockIdx.x * N_EXPERTS + threadIdx.x] = h[threadIdx.x];
}

// ---------------- Phase 2: scan ----------------
__global__ __launch_bounds__(256) void scan_kernel(int* __restrict__ hist,
    int* __restrict__ counts, int* __restrict__ offsets)
{
    __shared__ int sh[ROUTER_BLOCKS * N_EXPERTS];
    __shared__ int tot[N_EXPERTS], off[N_EXPERTS];
    int tid = threadIdx.x;
    *(int4*)&sh[tid * 8]     = *(const int4*)&hist[tid * 8];
    *(int4*)&sh[tid * 8 + 4] = *(const int4*)&hist[tid * 8 + 4];
    __syncthreads();
    if (tid < N_EXPERTS) {
        int run = 0;
        for (int b = 0; b < ROUTER_BLOCKS; ++b) {
            int v = sh[b * 8 + tid];
            sh[b * 8 + tid] = run;
            run += v;
        }
        tot[tid] = run;
    }
    __syncthreads();
    if (tid == 0) {
        int run = 0;
        for (int e = 0; e < N_EXPERTS; ++e) {
            off[e] = run; offsets[e] = run; counts[e] = tot[e]; run += tot[e];
        }
    }
    __syncthreads();
    int4 a = *(const int4*)&sh[tid * 8];
    int4 b = *(const int4*)&sh[tid * 8 + 4];
    a.x += off[0]; a.y += off[1]; a.z += off[2]; a.w += off[3];
    b.x += off[4]; b.y += off[5]; b.z += off[6]; b.w += off[7];
    *(int4*)&hist[tid * 8]     = a;
    *(int4*)&hist[tid * 8 + 4] = b;
}

// ---------------- Phase 3: scatter ----------------
__global__ __launch_bounds__(256) void order_kernel(const int* __restrict__ eidx,
    const int* __restrict__ localpos, const int* __restrict__ hist,
    int* __restrict__ order)
{
    int t = blockIdx.x * 256 + threadIdx.x;
    int base = hist[(t >> 6) * N_EXPERTS + eidx[t]];
    order[base + localpos[t]] = t;
}

// ---------------- Merged weight transposes (both enc and dec in one launch) ----------------
__global__ __launch_bounds__(256) void transpose_both(const float* __restrict__ enc,
    const float* __restrict__ dec, _Float16* __restrict__ encT, _Float16* __restrict__ decT)
{
    __shared__ _Float16 tile[64][72];
    int id = blockIdx.x;
    const float* W; _Float16* WT; int K, Nc, bx, by, bz;
    if (id < 3072) {
        W = enc; WT = encT; K = D_IN; Nc = EXPERT_DIM;
        bx = id & 31; by = (id >> 5) % 12; bz = id / 384;
    } else {
        int id2 = id - 3072;
        W = dec; WT = decT; K = EXPERT_DIM; Nc = D_IN;
        bx = id2 % 12; by = (id2 / 12) & 31; bz = id2 / 384;
    }
    size_t esz = (size_t)K * Nc;
    const float* We = W + (size_t)bz * esz;
    _Float16* WTe = WT + (size_t)bz * esz;
    int n0 = bx * 64, k0 = by * 64;
    int tr = threadIdx.x >> 4;
    int tc = threadIdx.x & 15;
#pragma unroll
    for (int rr = 0; rr < 64; rr += 16) {
        int k = k0 + rr + tr;
        float4 v = *(const float4*)(We + (size_t)k * Nc + n0 + tc * 4);
        tile[tc * 4 + 0][rr + tr] = (_Float16)v.x;
        tile[tc * 4 + 1][rr + tr] = (_Float16)v.y;
        tile[tc * 4 + 2][rr + tr] = (_Float16)v.z;
        tile[tc * 4 + 3][rr + tr] = (_Float16)v.w;
    }
    __syncthreads();
#pragma unroll
    for (int p = 0; p < 2; ++p) {
        int idp = threadIdx.x + p * 256;
        int r = idp >> 3, ch = idp & 7;
        half8 v = *(const half8*)&tile[r][ch * 8];
        *(half8*)(WTe + (size_t)(n0 + r) * K + k0 + ch * 8) = v;
    }
}

// Staging halves: 2 glds16 each (A pair, then B pair)
#define STAGE_A(bufp, k0h)                                      \
    do {                                                        \
        glds16(pa0 + (k0h), (bufp) + st_base);                  \
        glds16(pa1 + (k0h), (bufp) + st_base + 512);            \
    } while (0)
#define STAGE_B(bufp, k0h)                                      \
    do {                                                        \
        glds16(pb0 + (k0h), (bufp) + 8192 + st_base);           \
        glds16(pb1 + (k0h), (bufp) + 8192 + st_base + 512);     \
    } while (0)

// ---------------- Encode GEMM 256x256 BK=32 NBUF=4, 2-phase interleave ----------------
// grid 4096: e = id&7 (expert == XCD), j = id>>3: nt = j&7, mt = j>>3.
__global__ __launch_bounds__(512, 2) void encode_kernel(const _Float16* __restrict__ act_h,
    const _Float16* __restrict__ encT, const int* __restrict__ order,
    const int* __restrict__ counts, const int* __restrict__ offsets,
    _Float16* __restrict__ latent)
{
    int id = blockIdx.x;
    int e = id & 7;
    int j = id >> 3;
    int nt = j & 7;
    int mt = j >> 3;

    int n_e = counts[e];
    if (mt * 256 >= n_e) return;
    int slot0 = offsets[e] + mt * 256;
    int mrem = n_e - mt * 256;

    __shared__ _Float16 lds[4][16384];
    __shared__ int s_tok[256];

    int tid = threadIdx.x;
    if (tid < 256) s_tok[tid] = (tid < mrem) ? order[slot0 + tid] : order[slot0];
    __syncthreads();

    int w = tid >> 6, lane = tid & 63;
    int wm = w >> 2, wn = w & 3;
    int mrow = lane & 15;

    int st_base = w * 1024 + lane * 8;
    int c_st = ((lane & 3) - ((lane >> 3) & 3)) & 3;
    int r_in = lane >> 2;
    const _Float16* Be = encT + (size_t)e * D_IN * EXPERT_DIM + (size_t)(nt * 256) * D_IN;
    const _Float16* pa0 = act_h + (size_t)s_tok[w * 32 + r_in] * D_IN + c_st * 8;
    const _Float16* pa1 = act_h + (size_t)s_tok[w * 32 + 16 + r_in] * D_IN + c_st * 8;
    const _Float16* pb0 = Be + (size_t)(w * 32 + r_in) * D_IN + c_st * 8;
    const _Float16* pb1 = Be + (size_t)(w * 32 + 16 + r_in) * D_IN + c_st * 8;

    int fo = (((lane >> 4) + (mrow >> 1)) & 3) * 8;
    int aoff = (wm * 128 + mrow) * 32 + fo;          // + i*512
    int boff = 8192 + (wn * 64 + mrow) * 32 + fo;    // + j*512

    floatx4 acc[8][4];
#pragma unroll
    for (int i = 0; i < 8; ++i)
#pragma unroll
        for (int jj = 0; jj < 4; ++jj) acc[i][jj] = (floatx4){0.f, 0.f, 0.f, 0.f};

    const int T = D_IN / 32;   // 24
    STAGE_A(&lds[0][0], 0);  STAGE_B(&lds[0][0], 0);
    STAGE_A(&lds[1][0], 32); STAGE_B(&lds[1][0], 32);
    STAGE_A(&lds[2][0], 64); STAGE_B(&lds[2][0], 64);
    __builtin_amdgcn_s_waitcnt(WAIT_VM8);     // tile 0 landed (1,2 in flight)
    __builtin_amdgcn_s_barrier();

#pragma unroll 1
    for (int t = 0; t < T; ++t) {
        _Float16* cur = &lds[t & 3][0];
        _Float16* nx3 = &lds[(t + 3) & 3][0];
        int k3 = (t + 3) * 32;
        // ---- phase A: read A(i0-3)+B, stage A-half of t+3, MFMA i0-3 ----
        half8 af0[4], bf[4];
#pragma unroll
        for (int i = 0; i < 4; ++i) af0[i] = *(const half8*)&cur[aoff + i * 512];
#pragma unroll
        for (int jj = 0; jj < 4; ++jj) bf[jj] = *(const half8*)&cur[boff + jj * 512];
        if (t + 3 < T) STAGE_A(nx3, k3);
        __builtin_amdgcn_s_barrier();
        __builtin_amdgcn_s_setprio(1);
#pragma unroll
        for (int i = 0; i < 4; ++i)
#pragma unroll
            for (int jj = 0; jj < 4; ++jj)
                acc[i][jj] = __builtin_amdgcn_mfma_f32_16x16x32_f16(af0[i], bf[jj], acc[i][jj], 0, 0, 0);
        __builtin_amdgcn_s_setprio(0);
        __builtin_amdgcn_s_barrier();
        // ---- phase B: read A(i4-7), stage B-half of t+3, MFMA i4-7 ----
        half8 af1[4];
#pragma unroll
        for (int i = 0; i < 4; ++i) af1[i] = *(const half8*)&cur[aoff + (i + 4) * 512];
        if (t + 3 < T) STAGE_B(nx3, k3);
        __builtin_amdgcn_s_barrier();
        __builtin_amdgcn_s_setprio(1);
#pragma unroll
        for (int i = 0; i < 4; ++i)
#pragma unroll
            for (int jj = 0; jj < 4; ++jj)
                acc[i + 4][jj] = __builtin_amdgcn_mfma_f32_16x16x32_f16(af1[i], bf[jj], acc[i + 4][jj], 0, 0, 0);
        __builtin_amdgcn_s_setprio(0);
        // ---- iter boundary: counted vmcnt, then barrier -> tile t+1 ready for all ----
        if (t + 1 < T) {
            if (t + 3 < T)      __builtin_amdgcn_s_waitcnt(WAIT_VM8);
            else if (t + 2 < T) __builtin_amdgcn_s_waitcnt(WAIT_VM4);
            else                __builtin_amdgcn_s_waitcnt(WAIT_VM0);
            __builtin_amdgcn_s_barrier();
        }
    }

    // epilogue: ReLU -> latent f16
#pragma unroll
    for (int i = 0; i < 8; ++i) {
        int row0 = wm * 128 + i * 16 + (lane >> 4) * 4;
#pragma unroll
        for (int jj = 0; jj < 4; ++jj) {
            int col = nt * 256 + wn * 64 + jj * 16 + mrow;
#pragma unroll
            for (int r = 0; r < 4; ++r) {
                int row = row0 + r;
                if (row < mrem) {
                    float v = acc[i][jj][r];
                    v = v > 0.f ? v : 0.f;
                    latent[(size_t)(slot0 + row) * EXPERT_DIM + col] = (_Float16)v;
                }
            }
        }
    }
}

// ---------------- Decode GEMM 256x256 BK=32 NBUF=4, 2-phase interleave ----------------
// grid 1536: e = id&7, j = id>>3: nt = j%3, mt = j/3. Worst expert 27 blocks/XCD <= 32.
__global__ __launch_bounds__(512, 2) void decode_kernel(const _Float16* __restrict__ latent,
    const _Float16* __restrict__ decT, const int* __restrict__ order,
    const int* __restrict__ counts, const int* __restrict__ offsets,
    const float* __restrict__ prob, const float* __restrict__ pre_b,
    float* __restrict__ out)
{
    int id = blockIdx.x;
    int e = id & 7;
    int j = id >> 3;
    int nt = j % 3;
    int mt = j / 3;

    int n_e = counts[e];
    if (mt * 256 >= n_e) return;
    int slot0 = offsets[e] + mt * 256;
    int mrem = n_e - mt * 256;

    __shared__ _Float16 lds[4][16384];
    __shared__ int s_tok[256];
    __shared__ float s_p[256];

    int tid = threadIdx.x;
    if (tid < 256) {
        int tok = (tid < mrem) ? order[slot0 + tid] : order[slot0];
        s_tok[tid] = tok;
        s_p[tid] = prob[tok];
    }
    __syncthreads();

    int w = tid >> 6, lane = tid & 63;
    int wm = w >> 2, wn = w & 3;
    int mrow = lane & 15;

    int st_base = w * 1024 + lane * 8;
    int c_st = ((lane & 3) - ((lane >> 3) & 3)) & 3;
    int r_in = lane >> 2;
    const _Float16* Ae = latent + (size_t)slot0 * EXPERT_DIM;   // latent padded by 256 rows
    const _Float16* Be = decT + (size_t)e * EXPERT_DIM * D_IN + (size_t)(nt * 256) * EXPERT_DIM;
    const _Float16* pa0 = Ae + (size_t)(w * 32 + r_in) * EXPERT_DIM + c_st * 8;
    const _Float16* pa1 = Ae + (size_t)(w * 32 + 16 + r_in) * EXPERT_DIM + c_st * 8;
    const _Float16* pb0 = Be + (size_t)(w * 32 + r_in) * EXPERT_DIM + c_st * 8;
    const _Float16* pb1 = Be + (size_t)(w * 32 + 16 + r_in) * EXPERT_DIM + c_st * 8;

    int fo = (((lane >> 4) + (mrow >> 1)) & 3) * 8;
    int aoff = (wm * 128 + mrow) * 32 + fo;
    int boff = 8192 + (wn * 64 + mrow) * 32 + fo;

    floatx4 acc[8][4];
#pragma unroll
    for (int i = 0; i < 8; ++i)
#pragma unroll
        for (int jj = 0; jj < 4; ++jj) acc[i][jj] = (floatx4){0.f, 0.f, 0.f, 0.f};

    const int T = EXPERT_DIM / 32;   // 64
    STAGE_A(&lds[0][0], 0);  STAGE_B(&lds[0][0], 0);
    STAGE_A(&lds[1][0], 32); STAGE_B(&lds[1][0], 32);
    STAGE_A(&lds[2][0], 64); STAGE_B(&lds[2][0], 64);
    __builtin_amdgcn_s_waitcnt(WAIT_VM8);
    __builtin_amdgcn_s_barrier();

#pragma unroll 1
    for (int t = 0; t < T; ++t) {
        _Float16* cur = &lds[t & 3][0];
        _Float16* nx3 = &lds[(t + 3) & 3][0];
        int k3 = (t + 3) * 32;
        half8 af0[4], bf[4];
#pragma unroll
        for (int i = 0; i < 4; ++i) af0[i] = *(const half8*)&cur[aoff + i * 512];
#pragma unroll
        for (int jj = 0; jj < 4; ++jj) bf[jj] = *(const half8*)&cur[boff + jj * 512];
        if (t + 3 < T) STAGE_A(nx3, k3);
        __builtin_amdgcn_s_barrier();
        __builtin_amdgcn_s_setprio(1);
#pragma unroll
        for (int i = 0; i < 4; ++i)
#pragma unroll
            for (int jj = 0; jj < 4; ++jj)
                acc[i][jj] = __builtin_amdgcn_mfma_f32_16x16x32_f16(af0[i], bf[jj], acc[i][jj], 0, 0, 0);
        __builtin_amdgcn_s_setprio(0);
        __builtin_amdgcn_s_barrier();
        half8 af1[4];
#pragma unroll
        for (int i = 0; i < 4; ++i) af1[i] = *(const half8*)&cur[aoff + (i + 4) * 512];
        if (t + 3 < T) STAGE_B(nx3, k3);
        __builtin_amdgcn_s_barrier();
        __builtin_amdgcn_s_setprio(1);
#pragma unroll
        for (int i = 0; i < 4; ++i)
#pragma unroll
            for (int jj = 0; jj < 4; ++jj)
                acc[i + 4][jj] = __builtin_amdgcn_mfma_f32_16x16x32_f16(af1[i], bf[jj], acc[i + 4][jj], 0, 0, 0);
        __builtin_amdgcn_s_setprio(0);
        if (t + 1 < T) {
            if (t + 3 < T)      __builtin_amdgcn_s_waitcnt(WAIT_VM8);
            else if (t + 2 < T) __builtin_amdgcn_s_waitcnt(WAIT_VM4);
            else                __builtin_amdgcn_s_waitcnt(WAIT_VM0);
            __builtin_amdgcn_s_barrier();
        }
    }

    // epilogue: prob-scale + bias, scatter to out (fp32)
#pragma unroll
    for (int i = 0; i < 8; ++i) {
        int row0 = wm * 128 + i * 16 + (lane >> 4) * 4;
#pragma unroll
        for (int jj = 0; jj < 4; ++jj) {
            int col = nt * 256 + wn * 64 + jj * 16 + mrow;
            float pb = pre_b[col];
#pragma unroll
            for (int r = 0; r < 4; ++r) {
                int row = row0 + r;
                if (row < mrem) {
                    out[(size_t)s_tok[row] * D_IN + col] = s_p[row] * acc[i][jj][r] + pb;
                }
            }
        }
    }
}

extern "C" void kernel_launch(void* const* d_in, const int* in_sizes, int n_in,
                              void* d_out, int out_size, void* d_ws, size_t ws_size,
                              hipStream_t stream)
{
    const float* act      = (const float*)d_in[0];
    const float* pre_b    = (const float*)d_in[1];
    const float* enc      = (const float*)d_in[2];
    const float* dec      = (const float*)d_in[3];
    const float* router_b = (const float*)d_in[4];
    const float* router   = (const float*)d_in[5];
    float* out = (float*)d_out;

    char* w = (char*)d_ws;
    int* counts  = (int*)w;  w += 256;
    int* offsets = (int*)w;  w += 256;
    int* hist    = (int*)w;  w += ROUTER_BLOCKS * N_EXPERTS * 4;
    int* eidx    = (int*)w;  w += N_TOKENS * 4;
    int* lpos    = (int*)w;  w += N_TOKENS * 4;
    int* order   = (int*)w;  w += N_TOKENS * 4;
    float* prob  = (float*)w; w += N_TOKENS * 4;
    _Float16* act_h  = (_Float16*)w; w += (size_t)N_TOKENS * D_IN * 2;
    _Float16* encT   = (_Float16*)w; w += (size_t)N_EXPERTS * D_IN * EXPERT_DIM * 2;
    _Float16* decT   = (_Float16*)w; w += (size_t)N_EXPERTS * D_IN * EXPERT_DIM * 2;
    _Float16* latent = (_Float16*)w; w += (size_t)(N_TOKENS + 256) * EXPERT_DIM * 2;

    router_convert<<<ROUTER_BLOCKS, 256, 0, stream>>>(act, router_b, router, act_h, prob, lpos, eidx, hist);
    scan_kernel<<<1, 256, 0, stream>>>(hist, counts, offsets);
    order_kernel<<<N_TOKENS / 256, 256, 0, stream>>>(eidx, lpos, hist, order);

    transpose_both<<<6144, 256, 0, stream>>>(enc, dec, encT, decT);

    encode_kernel<<<4096, 512, 0, stream>>>(act_h, encT, order, counts, offsets, latent);
    decode_kernel<<<1536, 512, 0, stream>>>(latent, decT, order, counts, offsets, prob, pre_b, out);
}

// Round 8
// 367.254 us; speedup vs baseline: 1.0980x; 1.0093x over previous
//
#include <hip/hip_runtime.h>
#include <hip/hip_bf16.h>
#include <hip/hip_fp16.h>

#define N_TOKENS 16384
#define D_IN 768
#define N_EXPERTS 8
#define EXPERT_DIM 2048

#define ROUTER_BLOCKS 256
#define TOK_PER_BLOCK 64

typedef _Float16 half8 __attribute__((ext_vector_type(8)));
typedef _Float16 half4 __attribute__((ext_vector_type(4)));
typedef float floatx4 __attribute__((ext_vector_type(4)));

// ---- 256x256 GEMM, BK=32, NBUF=4, depth-3 prefetch, 2-phase/K-step interleave ----
// Addressing/swizzle identical to r6/r7 (SQ_LDS_BANK_CONFLICT == 0 verified):
//   store: phys chunk lane&3 <- logical chunk c_st = ((lane&3)-((lane>>3)&3))&3
//   read:  fo = (((lane>>4)+(mrow>>1))&3)*8
// r8 NEW: OPERAND-SWAPPED MFMA: acc[i][jj] = mfma(nf[i], mf[jj], acc) puts the
// N-dim in the C-layout's (lane>>4)*4+reg axis -> 4 consecutive acc regs span 4
// consecutive output COLUMNS -> half4/float4 epilogue stores (was 128 scalar
// stores/thread). Fragment addressing is symmetric (row=lane&15, k=lane>>4*8),
// so LDS layout/staging/schedule are unchanged.

// s_waitcnt imm (gfx9): vmcnt[3:0] | expcnt<<4 | lgkmcnt<<8 | vmcnt[5:4]<<14
#define WAIT_VM8  0xF78
#define WAIT_VM4  0xF74
#define WAIT_VM0  0xF70

__device__ __forceinline__ void glds16(const _Float16* g, _Float16* l) {
    __builtin_amdgcn_global_load_lds(
        (const __attribute__((address_space(1))) unsigned int*)g,
        (__attribute__((address_space(3))) unsigned int*)l, 16, 0, 0);
}

// ---------------- prep: fused {router + act->f16} U {enc,dec transposes} ----------------
// blocks [0,256): router+convert. blocks [256, 6400): weight transpose tiles.
__global__ __launch_bounds__(256) void prep_kernel(const float* __restrict__ act,
    const float* __restrict__ router_b, const float* __restrict__ router,
    const float* __restrict__ enc, const float* __restrict__ dec,
    _Float16* __restrict__ act_h, float* __restrict__ prob, int* __restrict__ localpos,
    int* __restrict__ eidx, int* __restrict__ hist,
    _Float16* __restrict__ encT, _Float16* __restrict__ decT)
{
    __shared__ _Float16 tile[64][72];
    __shared__ int h[N_EXPERTS];
    int id = blockIdx.x;

    if (id < ROUTER_BLOCKS) {
        // ---- router + convert ----
        if (threadIdx.x < N_EXPERTS) h[threadIdx.x] = 0;
        __syncthreads();

        int wave = threadIdx.x >> 6, lane = threadIdx.x & 63;
        float rb[3][4];
#pragma unroll
        for (int c = 0; c < 3; ++c) {
            float4 v = *(const float4*)(router_b + lane * 4 + c * 256);
            rb[c][0] = v.x; rb[c][1] = v.y; rb[c][2] = v.z; rb[c][3] = v.w;
        }

#pragma unroll 1
        for (int it = 0; it < 16; ++it) {
            int t = id * TOK_PER_BLOCK + wave * 16 + it;
            const float* arow = act + (size_t)t * D_IN;
            float acc[8];
#pragma unroll
            for (int e = 0; e < 8; ++e) acc[e] = 0.f;
#pragma unroll
            for (int c = 0; c < 3; ++c) {
                int i0 = lane * 4 + c * 256;
                float4 v = *(const float4*)(arow + i0);
                half4 hv;
                hv[0] = (_Float16)v.x; hv[1] = (_Float16)v.y;
                hv[2] = (_Float16)v.z; hv[3] = (_Float16)v.w;
                *(half4*)(act_h + (size_t)t * D_IN + i0) = hv;
                float va[4] = {v.x, v.y, v.z, v.w};
#pragma unroll
                for (int q = 0; q < 4; ++q) {
                    float a = va[q] - rb[c][q];
                    const float* r = router + (size_t)(i0 + q) * 8;
#pragma unroll
                    for (int e = 0; e < 8; ++e) acc[e] += a * r[e];
                }
            }
#pragma unroll
            for (int s = 32; s > 0; s >>= 1) {
#pragma unroll
                for (int e = 0; e < 8; ++e) acc[e] += __shfl_down(acc[e], s, 64);
            }
            if (lane == 0) {
                float m = acc[0]; int ai = 0;
#pragma unroll
                for (int e = 1; e < 8; ++e) if (acc[e] > m) { m = acc[e]; ai = e; }
                float s = 0.f;
#pragma unroll
                for (int e = 0; e < 8; ++e) s += __expf(acc[e] - m);
                prob[t] = 1.0f / s;
                eidx[t] = ai;
                localpos[t] = atomicAdd(&h[ai], 1);
            }
        }
        __syncthreads();
        if (threadIdx.x < N_EXPERTS) hist[id * N_EXPERTS + threadIdx.x] = h[threadIdx.x];
        return;
    }

    // ---- weight transpose ----
    int id2 = id - ROUTER_BLOCKS;
    const float* W; _Float16* WT; int K, Nc, bx, by, bz;
    if (id2 < 3072) {
        W = enc; WT = encT; K = D_IN; Nc = EXPERT_DIM;
        bx = id2 & 31; by = (id2 >> 5) % 12; bz = id2 / 384;
    } else {
        int id3 = id2 - 3072;
        W = dec; WT = decT; K = EXPERT_DIM; Nc = D_IN;
        bx = id3 % 12; by = (id3 / 12) & 31; bz = id3 / 384;
    }
    size_t esz = (size_t)K * Nc;
    const float* We = W + (size_t)bz * esz;
    _Float16* WTe = WT + (size_t)bz * esz;
    int n0 = bx * 64, k0 = by * 64;
    int tr = threadIdx.x >> 4;
    int tc = threadIdx.x & 15;
#pragma unroll
    for (int rr = 0; rr < 64; rr += 16) {
        int k = k0 + rr + tr;
        float4 v = *(const float4*)(We + (size_t)k * Nc + n0 + tc * 4);
        tile[tc * 4 + 0][rr + tr] = (_Float16)v.x;
        tile[tc * 4 + 1][rr + tr] = (_Float16)v.y;
        tile[tc * 4 + 2][rr + tr] = (_Float16)v.z;
        tile[tc * 4 + 3][rr + tr] = (_Float16)v.w;
    }
    __syncthreads();
#pragma unroll
    for (int p = 0; p < 2; ++p) {
        int idp = threadIdx.x + p * 256;
        int r = idp >> 3, ch = idp & 7;
        half8 v = *(const half8*)&tile[r][ch * 8];
        *(half8*)(WTe + (size_t)(n0 + r) * K + k0 + ch * 8) = v;
    }
}

// ---------------- order + inline redundant scan (replaces scan_kernel + order_kernel) ----------------
// 64 blocks x 256 threads. Each block computes the full hist scan in LDS (Hillis-Steele
// over 256 router-blocks x 8 experts), then scatters its 256 tokens. Block 0 also
// writes counts/offsets for the GEMMs.
__global__ __launch_bounds__(256) void order_scan_kernel(const int* __restrict__ eidx,
    const int* __restrict__ localpos, const int* __restrict__ hist,
    int* __restrict__ order, int* __restrict__ counts, int* __restrict__ offsets)
{
    __shared__ int sh[ROUTER_BLOCKS * N_EXPERTS];
    int tid = threadIdx.x;
    int4 a = ((const int4*)hist)[tid * 2];
    int4 b = ((const int4*)hist)[tid * 2 + 1];
    int o[8] = {a.x, a.y, a.z, a.w, b.x, b.y, b.z, b.w};
    int v[8];
#pragma unroll
    for (int e = 0; e < 8; ++e) { v[e] = o[e]; sh[tid * 8 + e] = v[e]; }
    __syncthreads();
#pragma unroll 1
    for (int s = 1; s < 256; s <<= 1) {
        int t2[8];
        if (tid >= s) {
#pragma unroll
            for (int e = 0; e < 8; ++e) t2[e] = sh[(tid - s) * 8 + e];
        }
        __syncthreads();
        if (tid >= s) {
#pragma unroll
            for (int e = 0; e < 8; ++e) { v[e] += t2[e]; sh[tid * 8 + e] = v[e]; }
        }
        __syncthreads();
    }
    // totals + expert offsets (every thread, registers)
    int tot[8];
#pragma unroll
    for (int e = 0; e < 8; ++e) tot[e] = sh[255 * 8 + e];
    int eo[8]; int run = 0;
#pragma unroll
    for (int e = 0; e < 8; ++e) { eo[e] = run; run += tot[e]; }
    __syncthreads();
    // final base per (router-block, expert): expert offset + exclusive block prefix
#pragma unroll
    for (int e = 0; e < 8; ++e) sh[tid * 8 + e] = eo[e] + v[e] - o[e];
    __syncthreads();

    if (blockIdx.x == 0 && tid < 8) { counts[tid] = tot[tid]; offsets[tid] = eo[tid]; }

    int t = blockIdx.x * 256 + tid;
    int base = sh[(t >> 6) * 8 + eidx[t]];
    order[base + localpos[t]] = t;
}

// Staging halves: 2 glds16 each (A pair, then B pair)
#define STAGE_A(bufp, k0h)                                      \
    do {                                                        \
        glds16(pa0 + (k0h), (bufp) + st_base);                  \
        glds16(pa1 + (k0h), (bufp) + st_base + 512);            \
    } while (0)
#define STAGE_B(bufp, k0h)                                      \
    do {                                                        \
        glds16(pb0 + (k0h), (bufp) + 8192 + st_base);           \
        glds16(pb1 + (k0h), (bufp) + 8192 + st_base + 512);     \
    } while (0)

// ---------------- Encode GEMM 256x256 BK=32 NBUF=4, 2-phase, swapped-operand epilogue ----------------
// grid 4096: e = id&7 (expert == XCD), j = id>>3: nt = j&7, mt = j>>3.
__global__ __launch_bounds__(512, 2) void encode_kernel(const _Float16* __restrict__ act_h,
    const _Float16* __restrict__ encT, const int* __restrict__ order,
    const int* __restrict__ counts, const int* __restrict__ offsets,
    _Float16* __restrict__ latent)
{
    int id = blockIdx.x;
    int e = id & 7;
    int j = id >> 3;
    int nt = j & 7;
    int mt = j >> 3;

    int n_e = counts[e];
    if (mt * 256 >= n_e) return;
    int slot0 = offsets[e] + mt * 256;
    int mrem = n_e - mt * 256;

    __shared__ _Float16 lds[4][16384];
    __shared__ int s_tok[256];

    int tid = threadIdx.x;
    if (tid < 256) s_tok[tid] = (tid < mrem) ? order[slot0 + tid] : order[slot0];
    __syncthreads();

    int w = tid >> 6, lane = tid & 63;
    int wm_n = w >> 2;          // 0..1: 128-wide n-slab
    int wn_m = w & 3;           // 0..3: 64-wide m-slab
    int mrow = lane & 15;

    int st_base = w * 1024 + lane * 8;
    int c_st = ((lane & 3) - ((lane >> 3) & 3)) & 3;
    int r_in = lane >> 2;
    const _Float16* Be = encT + (size_t)e * D_IN * EXPERT_DIM + (size_t)(nt * 256) * D_IN;
    const _Float16* pa0 = act_h + (size_t)s_tok[w * 32 + r_in] * D_IN + c_st * 8;
    const _Float16* pa1 = act_h + (size_t)s_tok[w * 32 + 16 + r_in] * D_IN + c_st * 8;
    const _Float16* pb0 = Be + (size_t)(w * 32 + r_in) * D_IN + c_st * 8;
    const _Float16* pb1 = Be + (size_t)(w * 32 + 16 + r_in) * D_IN + c_st * 8;

    int fo = (((lane >> 4) + (mrow >> 1)) & 3) * 8;
    int moff = (wn_m * 64 + mrow) * 32 + fo;            // act tile, frag jj at + jj*512
    int noff = 8192 + (wm_n * 128 + mrow) * 32 + fo;    // encT tile, frag i at + i*512

    floatx4 acc[8][4];
#pragma unroll
    for (int i = 0; i < 8; ++i)
#pragma unroll
        for (int jj = 0; jj < 4; ++jj) acc[i][jj] = (floatx4){0.f, 0.f, 0.f, 0.f};

    const int T = D_IN / 32;   // 24
    STAGE_A(&lds[0][0], 0);  STAGE_B(&lds[0][0], 0);
    STAGE_A(&lds[1][0], 32); STAGE_B(&lds[1][0], 32);
    STAGE_A(&lds[2][0], 64); STAGE_B(&lds[2][0], 64);
    __builtin_amdgcn_s_waitcnt(WAIT_VM8);     // tile 0 landed (1,2 in flight)
    __builtin_amdgcn_s_barrier();

#pragma unroll 1
    for (int t = 0; t < T; ++t) {
        _Float16* cur = &lds[t & 3][0];
        _Float16* nx3 = &lds[(t + 3) & 3][0];
        int k3 = (t + 3) * 32;
        // ---- phase A: read mf[0..3] + nf[0..3], stage A-half of t+3, MFMA i0-3 ----
        half8 mf[4], nf0[4];
#pragma unroll
        for (int jj = 0; jj < 4; ++jj) mf[jj] = *(const half8*)&cur[moff + jj * 512];
#pragma unroll
        for (int i = 0; i < 4; ++i) nf0[i] = *(const half8*)&cur[noff + i * 512];
        if (t + 3 < T) STAGE_A(nx3, k3);
        __builtin_amdgcn_s_barrier();
        __builtin_amdgcn_s_setprio(1);
#pragma unroll
        for (int i = 0; i < 4; ++i)
#pragma unroll
            for (int jj = 0; jj < 4; ++jj)
                acc[i][jj] = __builtin_amdgcn_mfma_f32_16x16x32_f16(nf0[i], mf[jj], acc[i][jj], 0, 0, 0);
        __builtin_amdgcn_s_setprio(0);
        __builtin_amdgcn_s_barrier();
        // ---- phase B: read nf[4..7], stage B-half of t+3, MFMA i4-7 ----
        half8 nf1[4];
#pragma unroll
        for (int i = 0; i < 4; ++i) nf1[i] = *(const half8*)&cur[noff + (i + 4) * 512];
        if (t + 3 < T) STAGE_B(nx3, k3);
        __builtin_amdgcn_s_barrier();
        __builtin_amdgcn_s_setprio(1);
#pragma unroll
        for (int i = 0; i < 4; ++i)
#pragma unroll
            for (int jj = 0; jj < 4; ++jj)
                acc[i + 4][jj] = __builtin_amdgcn_mfma_f32_16x16x32_f16(nf1[i], mf[jj], acc[i + 4][jj], 0, 0, 0);
        __builtin_amdgcn_s_setprio(0);
        // ---- iter boundary: counted vmcnt, then barrier ----
        if (t + 1 < T) {
            if (t + 3 < T)      __builtin_amdgcn_s_waitcnt(WAIT_VM8);
            else if (t + 2 < T) __builtin_amdgcn_s_waitcnt(WAIT_VM4);
            else                __builtin_amdgcn_s_waitcnt(WAIT_VM0);
            __builtin_amdgcn_s_barrier();
        }
    }

    // epilogue: ReLU -> latent f16, half4 stores (4 consecutive n per store)
#pragma unroll
    for (int i = 0; i < 8; ++i) {
        int ncol = nt * 256 + wm_n * 128 + i * 16 + (lane >> 4) * 4;
#pragma unroll
        for (int jj = 0; jj < 4; ++jj) {
            int m_row = wn_m * 64 + jj * 16 + mrow;
            if (m_row < mrem) {
                half4 hv;
#pragma unroll
                for (int r = 0; r < 4; ++r) {
                    float v = acc[i][jj][r];
                    hv[r] = (_Float16)(v > 0.f ? v : 0.f);
                }
                *(half4*)(latent + (size_t)(slot0 + m_row) * EXPERT_DIM + ncol) = hv;
            }
        }
    }
}

// ---------------- Decode GEMM 256x256 BK=32 NBUF=4, 2-phase, swapped-operand epilogue ----------------
// grid 1536: e = id&7, j = id>>3: nt = j%3, mt = j/3. Worst expert 27 blocks/XCD <= 32.
__global__ __launch_bounds__(512, 2) void decode_kernel(const _Float16* __restrict__ latent,
    const _Float16* __restrict__ decT, const int* __restrict__ order,
    const int* __restrict__ counts, const int* __restrict__ offsets,
    const float* __restrict__ prob, const float* __restrict__ pre_b,
    float* __restrict__ out)
{
    int id = blockIdx.x;
    int e = id & 7;
    int j = id >> 3;
    int nt = j % 3;
    int mt = j / 3;

    int n_e = counts[e];
    if (mt * 256 >= n_e) return;
    int slot0 = offsets[e] + mt * 256;
    int mrem = n_e - mt * 256;

    __shared__ _Float16 lds[4][16384];
    __shared__ int s_tok[256];
    __shared__ float s_p[256];

    int tid = threadIdx.x;
    if (tid < 256) {
        int tok = (tid < mrem) ? order[slot0 + tid] : order[slot0];
        s_tok[tid] = tok;
        s_p[tid] = prob[tok];
    }
    __syncthreads();

    int w = tid >> 6, lane = tid & 63;
    int wm_n = w >> 2;
    int wn_m = w & 3;
    int mrow = lane & 15;

    int st_base = w * 1024 + lane * 8;
    int c_st = ((lane & 3) - ((lane >> 3) & 3)) & 3;
    int r_in = lane >> 2;
    const _Float16* Ae = latent + (size_t)slot0 * EXPERT_DIM;   // latent padded by 256 rows
    const _Float16* Be = decT + (size_t)e * EXPERT_DIM * D_IN + (size_t)(nt * 256) * EXPERT_DIM;
    const _Float16* pa0 = Ae + (size_t)(w * 32 + r_in) * EXPERT_DIM + c_st * 8;
    const _Float16* pa1 = Ae + (size_t)(w * 32 + 16 + r_in) * EXPERT_DIM + c_st * 8;
    const _Float16* pb0 = Be + (size_t)(w * 32 + r_in) * EXPERT_DIM + c_st * 8;
    const _Float16* pb1 = Be + (size_t)(w * 32 + 16 + r_in) * EXPERT_DIM + c_st * 8;

    int fo = (((lane >> 4) + (mrow >> 1)) & 3) * 8;
    int moff = (wn_m * 64 + mrow) * 32 + fo;
    int noff = 8192 + (wm_n * 128 + mrow) * 32 + fo;

    floatx4 acc[8][4];
#pragma unroll
    for (int i = 0; i < 8; ++i)
#pragma unroll
        for (int jj = 0; jj < 4; ++jj) acc[i][jj] = (floatx4){0.f, 0.f, 0.f, 0.f};

    const int T = EXPERT_DIM / 32;   // 64
    STAGE_A(&lds[0][0], 0);  STAGE_B(&lds[0][0], 0);
    STAGE_A(&lds[1][0], 32); STAGE_B(&lds[1][0], 32);
    STAGE_A(&lds[2][0], 64); STAGE_B(&lds[2][0], 64);
    __builtin_amdgcn_s_waitcnt(WAIT_VM8);
    __builtin_amdgcn_s_barrier();

#pragma unroll 1
    for (int t = 0; t < T; ++t) {
        _Float16* cur = &lds[t & 3][0];
        _Float16* nx3 = &lds[(t + 3) & 3][0];
        int k3 = (t + 3) * 32;
        half8 mf[4], nf0[4];
#pragma unroll
        for (int jj = 0; jj < 4; ++jj) mf[jj] = *(const half8*)&cur[moff + jj * 512];
#pragma unroll
        for (int i = 0; i < 4; ++i) nf0[i] = *(const half8*)&cur[noff + i * 512];
        if (t + 3 < T) STAGE_A(nx3, k3);
        __builtin_amdgcn_s_barrier();
        __builtin_amdgcn_s_setprio(1);
#pragma unroll
        for (int i = 0; i < 4; ++i)
#pragma unroll
            for (int jj = 0; jj < 4; ++jj)
                acc[i][jj] = __builtin_amdgcn_mfma_f32_16x16x32_f16(nf0[i], mf[jj], acc[i][jj], 0, 0, 0);
        __builtin_amdgcn_s_setprio(0);
        __builtin_amdgcn_s_barrier();
        half8 nf1[4];
#pragma unroll
        for (int i = 0; i < 4; ++i) nf1[i] = *(const half8*)&cur[noff + (i + 4) * 512];
        if (t + 3 < T) STAGE_B(nx3, k3);
        __builtin_amdgcn_s_barrier();
        __builtin_amdgcn_s_setprio(1);
#pragma unroll
        for (int i = 0; i < 4; ++i)
#pragma unroll
            for (int jj = 0; jj < 4; ++jj)
                acc[i + 4][jj] = __builtin_amdgcn_mfma_f32_16x16x32_f16(nf1[i], mf[jj], acc[i + 4][jj], 0, 0, 0);
        __builtin_amdgcn_s_setprio(0);
        if (t + 1 < T) {
            if (t + 3 < T)      __builtin_amdgcn_s_waitcnt(WAIT_VM8);
            else if (t + 2 < T) __builtin_amdgcn_s_waitcnt(WAIT_VM4);
            else                __builtin_amdgcn_s_waitcnt(WAIT_VM0);
            __builtin_amdgcn_s_barrier();
        }
    }

    // epilogue: prob-scale + bias, float4 scatter (4 consecutive cols per store)
#pragma unroll
    for (int i = 0; i < 8; ++i) {
        int ncol = nt * 256 + wm_n * 128 + i * 16 + (lane >> 4) * 4;
        float4 pb = *(const float4*)(pre_b + ncol);
#pragma unroll
        for (int jj = 0; jj < 4; ++jj) {
            int m_row = wn_m * 64 + jj * 16 + mrow;
            if (m_row < mrem) {
                float sp = s_p[m_row];
                float4 ov;
                ov.x = sp * acc[i][jj][0] + pb.x;
                ov.y = sp * acc[i][jj][1] + pb.y;
                ov.z = sp * acc[i][jj][2] + pb.z;
                ov.w = sp * acc[i][jj][3] + pb.w;
                *(float4*)(out + (size_t)s_tok[m_row] * D_IN + ncol) = ov;
            }
        }
    }
}

extern "C" void kernel_launch(void* const* d_in, const int* in_sizes, int n_in,
                              void* d_out, int out_size, void* d_ws, size_t ws_size,
                              hipStream_t stream)
{
    const float* act      = (const float*)d_in[0];
    const float* pre_b    = (const float*)d_in[1];
    const float* enc      = (const float*)d_in[2];
    const float* dec      = (const float*)d_in[3];
    const float* router_b = (const float*)d_in[4];
    const float* router   = (const float*)d_in[5];
    float* out = (float*)d_out;

    char* w = (char*)d_ws;
    int* counts  = (int*)w;  w += 256;
    int* offsets = (int*)w;  w += 256;
    int* hist    = (int*)w;  w += ROUTER_BLOCKS * N_EXPERTS * 4;
    int* eidx    = (int*)w;  w += N_TOKENS * 4;
    int* lpos    = (int*)w;  w += N_TOKENS * 4;
    int* order   = (int*)w;  w += N_TOKENS * 4;
    float* prob  = (float*)w; w += N_TOKENS * 4;
    _Float16* act_h  = (_Float16*)w; w += (size_t)N_TOKENS * D_IN * 2;
    _Float16* encT   = (_Float16*)w; w += (size_t)N_EXPERTS * D_IN * EXPERT_DIM * 2;
    _Float16* decT   = (_Float16*)w; w += (size_t)N_EXPERTS * D_IN * EXPERT_DIM * 2;
    _Float16* latent = (_Float16*)w; w += (size_t)(N_TOKENS + 256) * EXPERT_DIM * 2;

    prep_kernel<<<6400, 256, 0, stream>>>(act, router_b, router, enc, dec,
                                          act_h, prob, lpos, eidx, hist, encT, decT);
    order_scan_kernel<<<N_TOKENS / 256, 256, 0, stream>>>(eidx, lpos, hist, order, counts, offsets);
    encode_kernel<<<4096, 512, 0, stream>>>(act_h, encT, order, counts, offsets, latent);
    decode_kernel<<<1536, 512, 0, stream>>>(latent, decT, order, counts, offsets, prob, pre_b, out);
}